// Round 8
// baseline (355.690 us; speedup 1.0000x reference)
//
#include <hip/hip_runtime.h>
#include <cstdint>
#include <cstddef>

#define BB 4
#define NN 100000
#define CC 80
#define NC (NN * CC)          // 8,000,000
#define KTOP 4096
#define PROP 100
#define HBINS 10248           // buckets for (float_bits>>12) - 0x3D000, covers (0.03125, 1.0]
#define BUCKET_BASE 0x3D000u
#define CAPB 16384
#define SPILLCAP 131072
#define T0BK 0x3F733u         // absolute bucket threshold: s >= 0.94989...
#define SPILL_LO (T0BK - BUCKET_BASE)     // 10035
#define SPILL_BINS (HBINS - SPILL_LO)     // 213
#define P1CAP 1024            // per-block LDS spill buffer entries
#define NSEL 512              // partial-selection target for NMS

// ws layout:
//   [0)        hist  : BB * HBINS * u32 = 163,968 B (zeroed)
//   [163968)   ctrl  : 128 B (zeroed)  b*8+{0:B1,1:cntAbove,2:nA,3:nB,4:nSpill}; ctrl[6]=p1 overflow, ctrl[7]=needFull
//   [164096)   candA : BB * KTOP * u64
//   [295168)   candB : BB * CAPB * u64
//   [819456)   spill : BB * SPILLCAP * u64
#define HIST_BYTES (BB * HBINS * 4)
#define CTRL_OFF   HIST_BYTES
#define ZERO_BYTES (HIST_BYTES + 128)
#define CANDA_OFF  (HIST_BYTES + 128)
#define CANDB_OFF  (CANDA_OFF + BB * KTOP * 8)
#define SPILL_OFF  (CANDB_OFF + BB * CAPB * 8)
#define WS_NEEDED  ((size_t)SPILL_OFF + (size_t)BB * SPILLCAP * 8)

// ---------------- FAST pass 1: filter s>=bucket(T0BK); LDS-staged spill ----------------
__global__ void k_pass1(const float* __restrict__ logits, const float* __restrict__ cent,
                        unsigned* __restrict__ ctrl, unsigned long long* __restrict__ spill) {
    int b = blockIdx.y;
    __shared__ unsigned long long lbuf[P1CAP];
    __shared__ unsigned lcnt, gbase, lflush;
    if (threadIdx.x == 0) lcnt = 0;
    __syncthreads();
    const float4* lg = (const float4*)(logits + (size_t)b * NC);
    const float* cb = cent + (size_t)b * NN;
    const int T4 = NC / 4;
    for (int i = blockIdx.x * blockDim.x + threadIdx.x; i < T4; i += gridDim.x * blockDim.x) {
        float4 v = lg[i];
        int n = i / 20;
        int c4 = (i - n * 20) * 4;
        float ce = cb[n];
        unsigned k0 = __float_as_uint(sqrtf(v.x * ce));
        unsigned k1 = __float_as_uint(sqrtf(v.y * ce));
        unsigned k2 = __float_as_uint(sqrtf(v.z * ce));
        unsigned k3 = __float_as_uint(sqrtf(v.w * ce));
        bool p0 = (c4 != 0) && ((k0 >> 12) >= T0BK);
        bool p1 = (k1 >> 12) >= T0BK;
        bool p2 = (k2 >> 12) >= T0BK;
        bool p3 = (k3 >> 12) >= T0BK;
        unsigned cnt = (unsigned)p0 + (unsigned)p1 + (unsigned)p2 + (unsigned)p3;
        if (cnt) {
            unsigned q = atomicAdd(&lcnt, cnt);
            unsigned f = (unsigned)i * 4u;
            if (p0) { if (q < P1CAP) lbuf[q] = ((unsigned long long)k0 << 32) | (unsigned)(~(f + 0)); q++; }
            if (p1) { if (q < P1CAP) lbuf[q] = ((unsigned long long)k1 << 32) | (unsigned)(~(f + 1)); q++; }
            if (p2) { if (q < P1CAP) lbuf[q] = ((unsigned long long)k2 << 32) | (unsigned)(~(f + 2)); q++; }
            if (p3) { if (q < P1CAP) lbuf[q] = ((unsigned long long)k3 << 32) | (unsigned)(~(f + 3)); }
        }
    }
    __syncthreads();
    if (threadIdx.x == 0) {
        unsigned n = lcnt;
        if (n > P1CAP) { atomicOr(&ctrl[6], 1u); n = P1CAP; }
        lflush = n;
        gbase = n ? atomicAdd(&ctrl[b * 8 + 4], n) : 0u;
    }
    __syncthreads();
    unsigned long long* sp = spill + (size_t)b * SPILLCAP;
    unsigned n = lflush, g0 = gbase;
    for (unsigned i = threadIdx.x; i < n; i += blockDim.x) {
        unsigned pos = g0 + i;
        if (pos < SPILLCAP) sp[pos] = lbuf[i];
    }
}

// ---------------- decide fast/slow path ----------------
__global__ void k_slowflag(unsigned* __restrict__ ctrl) {
    if (threadIdx.x == 0 && blockIdx.x == 0) {
        unsigned f = ctrl[6] ? 1u : 0u;
        for (int b = 0; b < BB; b++) {
            unsigned ns = ctrl[b * 8 + 4];
            if (ns < KTOP || ns > SPILLCAP) f = 1;
        }
        ctrl[7] = f;
    }
}

// ---------------- FAST: histogram the spill buffer ----------------
__global__ void k_hist_spill(const unsigned* __restrict__ ctrl,
                             const unsigned long long* __restrict__ spill,
                             unsigned* __restrict__ hist) {
    if (ctrl[7]) return;
    int b = blockIdx.y;
    __shared__ unsigned lh[SPILL_BINS];
    for (int i = threadIdx.x; i < SPILL_BINS; i += blockDim.x) lh[i] = 0;
    __syncthreads();
    unsigned ns = ctrl[b * 8 + 4];
    if (ns > SPILLCAP) ns = SPILLCAP;
    const unsigned long long* sp = spill + (size_t)b * SPILLCAP;
    for (unsigned i = blockIdx.x * blockDim.x + threadIdx.x; i < ns; i += gridDim.x * blockDim.x) {
        unsigned bits = (unsigned)(sp[i] >> 32);
        atomicAdd(&lh[(bits >> 12) - T0BK], 1u);
    }
    __syncthreads();
    unsigned* gh = hist + (size_t)b * HBINS + SPILL_LO;
    for (int i = threadIdx.x; i < SPILL_BINS; i += blockDim.x) {
        unsigned c = lh[i];
        if (c) atomicAdd(&gh[i], c);
    }
}

// ---------------- SLOW (guarded) full histogram ----------------
__global__ void k_hist(const float* __restrict__ logits, const float* __restrict__ cent,
                       unsigned* __restrict__ hist, const unsigned* __restrict__ ctrl) {
    if (ctrl[7] == 0) return;
    int b = blockIdx.y;
    __shared__ unsigned lh[HBINS];
    for (int i = threadIdx.x; i < HBINS; i += blockDim.x) lh[i] = 0;
    __syncthreads();
    const float4* lg = (const float4*)(logits + (size_t)b * NC);
    const float* cb = cent + (size_t)b * NN;
    const int T4 = NC / 4;
    for (int i = blockIdx.x * blockDim.x + threadIdx.x; i < T4; i += gridDim.x * blockDim.x) {
        float4 v = lg[i];
        int n = i / 20;
        int c4 = (i - n * 20) * 4;
        float ce = cb[n];
        float s;
        s = sqrtf(v.x * ce);
        if (c4 != 0 && s > 0.05f) atomicAdd(&lh[(__float_as_uint(s) >> 12) - BUCKET_BASE], 1u);
        s = sqrtf(v.y * ce);
        if (s > 0.05f) atomicAdd(&lh[(__float_as_uint(s) >> 12) - BUCKET_BASE], 1u);
        s = sqrtf(v.z * ce);
        if (s > 0.05f) atomicAdd(&lh[(__float_as_uint(s) >> 12) - BUCKET_BASE], 1u);
        s = sqrtf(v.w * ce);
        if (s > 0.05f) atomicAdd(&lh[(__float_as_uint(s) >> 12) - BUCKET_BASE], 1u);
    }
    __syncthreads();
    unsigned* gh = hist + (size_t)b * HBINS;
    for (int i = threadIdx.x; i < HBINS; i += blockDim.x) {
        unsigned c = lh[i];
        if (c) atomicAdd(&gh[i], c);
    }
}

// ---------------- SLOW-only: find boundary bucket B1 per batch ----------------
__global__ void k_select(const unsigned* __restrict__ hist, unsigned* __restrict__ ctrl) {
    if (ctrl[7] == 0) return;   // fast path: k_mega computes B1 itself
    int b = blockIdx.x;
    int t = threadIdx.x;
    const unsigned* h = hist + (size_t)b * HBINS;
    __shared__ unsigned ssum[256];
    const int CH = (HBINS + 255) / 256;  // 41
    unsigned acc0 = 0;
    for (int i = 0; i < CH; i++) {
        int idx = t * CH + i;
        if (idx < HBINS) acc0 += h[idx];
    }
    ssum[t] = acc0;
    __syncthreads();
    for (int off = 1; off < 256; off <<= 1) {
        unsigned v = (t + off < 256) ? ssum[t + off] : 0u;
        __syncthreads();
        ssum[t] += v;
        __syncthreads();
    }
    unsigned acc = (t < 255) ? ssum[t + 1] : 0u;
    for (int i = CH - 1; i >= 0; i--) {
        int idx = t * CH + i;
        if (idx >= HBINS) continue;
        unsigned cnt = h[idx];
        unsigned na = acc + cnt;
        if (na >= KTOP && acc < KTOP) {
            ctrl[b * 8 + 0] = (unsigned)idx;
            ctrl[b * 8 + 1] = acc;
        }
        acc = na;
    }
}

// ---------------- SLOW (guarded) full compact ----------------
__global__ void k_compact(const float* __restrict__ logits, const float* __restrict__ cent,
                          unsigned* __restrict__ ctrl,
                          unsigned long long* __restrict__ candA,
                          unsigned long long* __restrict__ candB) {
    if (ctrl[7] == 0) return;
    int b = blockIdx.y;
    unsigned B1 = ctrl[b * 8 + 0];
    const float4* lg = (const float4*)(logits + (size_t)b * NC);
    const float* cb = cent + (size_t)b * NN;
    const int T4 = NC / 4;
    unsigned long long* gA = candA + (size_t)b * KTOP;
    unsigned long long* gB = candB + (size_t)b * CAPB;
    for (int i = blockIdx.x * blockDim.x + threadIdx.x; i < T4; i += gridDim.x * blockDim.x) {
        float4 v = lg[i];
        int n = i / 20;
        int c4 = (i - n * 20) * 4;
        float ce = cb[n];
        float sv[4] = {v.x, v.y, v.z, v.w};
#pragma unroll
        for (int k = 0; k < 4; k++) {
            float s = sqrtf(sv[k] * ce);
            int c = c4 + k;
            if (c != 0 && s > 0.05f) {
                unsigned key = __float_as_uint(s);
                unsigned bk = (key >> 12) - BUCKET_BASE;
                if (bk >= B1) {
                    unsigned flat = (unsigned)(i * 4 + k);
                    unsigned long long pk = ((unsigned long long)key << 32) | (unsigned)(~flat);
                    if (bk > B1) {
                        unsigned p = atomicAdd(&ctrl[b * 8 + 2], 1u);
                        if (p < KTOP) gA[p] = pk;
                    } else {
                        unsigned p = atomicAdd(&ctrl[b * 8 + 3], 1u);
                        if (p < CAPB) gB[p] = pk;
                    }
                }
            }
        }
    }
}

// rank candB[0..nb) desc; keys with rank<m appended to sel[Sbase+rank].
__device__ void rank_append(const unsigned long long* gB, unsigned nb, unsigned m,
                            unsigned long long* sel, unsigned Sbase,
                            unsigned long long* scratch, int t) {
    unsigned nbr = (nb + 255u) & ~255u;
    for (unsigned ii = 0; ii < nbr; ii += 256) {
        unsigned i = ii + (unsigned)t;
        bool act = (i < nb);
        unsigned long long ki = act ? gB[i] : 0ull;
        unsigned rank = 0;
        for (unsigned c0 = 0; c0 < nb; c0 += 8192) {
            unsigned chunk = nb - c0;
            if (chunk > 8192) chunk = 8192;
            __syncthreads();
            for (unsigned j = (unsigned)t; j < chunk; j += 256) scratch[j] = gB[c0 + j];
            __syncthreads();
            if (act) for (unsigned j = 0; j < chunk; j++) rank += (scratch[j] > ki) ? 1u : 0u;
        }
        if (act && rank < m) sel[Sbase + rank] = ki;
    }
    __syncthreads();
}

// ---------------- MEGA: select+boundary+sort+NMS+output, one block per batch ----------------
__global__ void __launch_bounds__(256, 1) k_mega(
    const float* __restrict__ logits, const float* __restrict__ regress,
    const float* __restrict__ points, const float* __restrict__ cent,
    const unsigned* __restrict__ hist, const unsigned* __restrict__ ctrl,
    const unsigned long long* __restrict__ spill,
    const unsigned long long* __restrict__ candA, unsigned long long* __restrict__ candB,
    float* __restrict__ out) {
    int b = blockIdx.x, t = threadIdx.x, lane = t & 63;
    bool slow = ctrl[7] != 0;
    __shared__ unsigned long long sel[KTOP];   // 32 KB
    __shared__ float4 sbox[KTOP];              // 64 KB (scratch for ranking before decode)
    __shared__ unsigned ssum[256];
    __shared__ float4 kbox[PROP];
    __shared__ unsigned selAnc[PROP];
    __shared__ unsigned sv[8];                 // 0:B1 1:cntAbove 2:Bq 4:selcnt 5:kept 6:again 7:nbcnt
    unsigned long long* scratch = (unsigned long long*)sbox;   // 8192 u64

    // ---- suffix scan over global hist: B1/cntAbove + NSEL crossing Bq ----
    const unsigned* h = hist + (size_t)b * HBINS;
    const int CH = (HBINS + 255) / 256;  // 41
    unsigned a0 = 0;
    for (int i = 0; i < CH; i++) { int idx = t * CH + i; if (idx < HBINS) a0 += h[idx]; }
    ssum[t] = a0;
    __syncthreads();
    for (int off = 1; off < 256; off <<= 1) {
        unsigned v = (t + off < 256) ? ssum[t + off] : 0u;
        __syncthreads(); ssum[t] += v; __syncthreads();
    }
    if (t == 0) { sv[0] = 0; sv[1] = 0; sv[2] = 0; }
    __syncthreads();
    unsigned acc = (t < 255) ? ssum[t + 1] : 0u;
    for (int i = CH - 1; i >= 0; i--) {
        int idx = t * CH + i;
        if (idx >= HBINS) continue;
        unsigned cnt = h[idx];
        unsigned na = acc + cnt;
        if (na >= KTOP && acc < KTOP) { sv[0] = (unsigned)idx; sv[1] = acc; }
        if (na >= NSEL && acc < NSEL) { sv[2] = (unsigned)idx; }
        acc = na;
    }
    __syncthreads();
    unsigned B1 = slow ? ctrl[b * 8 + 0] : sv[0];
    unsigned cntAbove = slow ? ctrl[b * 8 + 1] : sv[1];
    unsigned Bq = sv[2];

    const unsigned long long* sp = spill + (size_t)b * SPILLCAP;
    const unsigned long long* gA = candA + (size_t)b * KTOP;
    unsigned long long* gB = candB + (size_t)b * CAPB;
    unsigned ns = 0, nA = 0;
    if (!slow) { ns = ctrl[b * 8 + 4]; if (ns > SPILLCAP) ns = SPILLCAP; }
    else       { nA = ctrl[b * 8 + 2]; if (nA > KTOP) nA = KTOP; }

    unsigned S = 0, totalCand = 0, m = 0, nb = 0;

    for (int round = 0; round < 2; round++) {
        if (t == 0) { sv[4] = 0; sv[5] = 0; sv[6] = 0; if (round == 0) sv[7] = 0; }
        __syncthreads();
        bool full = (round == 1) || (Bq <= B1);

        if (!slow) {
            for (unsigned i = t; i < ns; i += 256) {
                unsigned long long k = sp[i];
                unsigned bkt = ((unsigned)(k >> 32) >> 12) - BUCKET_BASE;
                bool psel = full ? (bkt > B1) : (bkt >= Bq);
                unsigned long long mm = __ballot(psel);
                if (mm) {
                    int ld = __ffsll(mm) - 1;
                    unsigned base = 0;
                    if (lane == ld) base = atomicAdd(&sv[4], (unsigned)__popcll(mm));
                    base = (unsigned)__shfl((int)base, ld);
                    if (psel) {
                        unsigned pos = base + (unsigned)__popcll(mm & ((1ull << lane) - 1ull));
                        if (pos < KTOP) sel[pos] = k;
                    }
                }
                if (round == 0) {
                    bool pb = (bkt == B1);
                    unsigned long long mb = __ballot(pb);
                    if (mb) {
                        int ld = __ffsll(mb) - 1;
                        unsigned base = 0;
                        if (lane == ld) base = atomicAdd(&sv[7], (unsigned)__popcll(mb));
                        base = (unsigned)__shfl((int)base, ld);
                        if (pb) {
                            unsigned pos = base + (unsigned)__popcll(mb & ((1ull << lane) - 1ull));
                            if (pos < CAPB) gB[pos] = k;
                        }
                    }
                }
            }
            __syncthreads();
            if (round == 0) {
                nb = sv[7]; if (nb > CAPB) nb = CAPB;
                unsigned cA = (Bq <= B1) ? sv[4] : cntAbove;
                if (cA > KTOP) cA = KTOP;
                m = (cA < KTOP) ? (KTOP - cA) : 0;
                if (m > nb) m = nb;
                totalCand = cA + m;
                if (totalCand > KTOP) totalCand = KTOP;
            }
        } else {
            for (unsigned i = t; i < nA; i += 256) {
                unsigned long long k = gA[i];
                unsigned bkt = ((unsigned)(k >> 32) >> 12) - BUCKET_BASE;
                bool psel = full || (bkt >= Bq);
                unsigned long long mm = __ballot(psel);
                if (mm) {
                    int ld = __ffsll(mm) - 1;
                    unsigned base = 0;
                    if (lane == ld) base = atomicAdd(&sv[4], (unsigned)__popcll(mm));
                    base = (unsigned)__shfl((int)base, ld);
                    if (psel) {
                        unsigned pos = base + (unsigned)__popcll(mm & ((1ull << lane) - 1ull));
                        if (pos < KTOP) sel[pos] = k;
                    }
                }
            }
            __syncthreads();
            if (round == 0) {
                nb = ctrl[b * 8 + 3]; if (nb > CAPB) nb = CAPB;
                m = (nA < KTOP) ? (KTOP - nA) : 0;
                if (m > nb) m = nb;
                totalCand = nA + m;
            }
        }
        S = sv[4]; if (S > KTOP) S = KTOP;
        if (full && m > 0 && S + m <= KTOP) {
            rank_append(gB, nb, m, sel, S, scratch, t);
            S += m;
        }
        __syncthreads();

        // pad + bitonic sort descending
        unsigned P2 = 2;
        while (P2 < S) P2 <<= 1;
        for (unsigned i = S + t; i < P2; i += 256) sel[i] = 0ull;
        __syncthreads();
        for (unsigned k2 = 2; k2 <= P2; k2 <<= 1) {
            for (unsigned j = k2 >> 1; j > 0; j >>= 1) {
                for (unsigned t2 = t; t2 < P2 / 2; t2 += 256) {
                    unsigned i = ((t2 & ~(j - 1)) << 1) | (t2 & (j - 1));
                    unsigned p2i = i + j;
                    bool dir = ((i & k2) == 0);
                    unsigned long long a = sel[i], c = sel[p2i];
                    if ((a < c) == dir) { sel[i] = c; sel[p2i] = a; }
                }
                __syncthreads();
            }
        }

        // decode boxes
        for (unsigned i = t; i < S; i += 256) {
            unsigned long long kk = sel[i];
            float4 bx = {0.f, 0.f, 0.f, 0.f};
            if (kk) {
                unsigned flat = ~(unsigned)kk;
                unsigned a = flat / CC;
                float px = points[a * 2 + 0], py = points[a * 2 + 1];
                const float* rg = regress + ((size_t)b * NN + a) * 4;
                bx.x = fminf(fmaxf(px - rg[0], 0.f), 1.f);
                bx.y = fminf(fmaxf(py - rg[1], 0.f), 1.f);
                bx.z = fminf(fmaxf(px + rg[2], 0.f), 1.f);
                bx.w = fminf(fmaxf(py + rg[3], 0.f), 1.f);
            }
            sbox[i] = bx;
        }
        __syncthreads();

        // single-wave scan, kept boxes cached in registers (lane owns slots lane, lane+64)
        if (t < 64) {
            float4 kb0 = {0, 0, 0, 0}, kb1 = {0, 0, 0, 0};
            unsigned kc0 = 0xFFFFFFFFu, kc1 = 0xFFFFFFFFu;
            int cnt = 0;
            for (unsigned i = 0; i < S && cnt < PROP; i++) {
                unsigned long long kk = sel[i];
                if (!kk) break;
                unsigned flat = ~(unsigned)kk;
                unsigned a = flat / CC;
                unsigned ccls = flat - a * CC;
                float4 c4 = sbox[i];
                float ca = (c4.z - c4.x) * (c4.w - c4.y);
                bool sup = false;
                if (lane < cnt && kc0 == ccls) {
                    float w = fmaxf(fminf(c4.z, kb0.z) - fmaxf(c4.x, kb0.x), 0.f);
                    float hh = fmaxf(fminf(c4.w, kb0.w) - fmaxf(c4.y, kb0.y), 0.f);
                    float inter = w * hh;
                    float ka = (kb0.z - kb0.x) * (kb0.w - kb0.y);
                    sup = inter / fmaxf(ca + ka - inter, 1e-9f) > 0.5f;
                }
                if (lane + 64 < cnt && kc1 == ccls) {
                    float w = fmaxf(fminf(c4.z, kb1.z) - fmaxf(c4.x, kb1.x), 0.f);
                    float hh = fmaxf(fminf(c4.w, kb1.w) - fmaxf(c4.y, kb1.y), 0.f);
                    float inter = w * hh;
                    float ka = (kb1.z - kb1.x) * (kb1.w - kb1.y);
                    sup = sup || (inter / fmaxf(ca + ka - inter, 1e-9f) > 0.5f);
                }
                if (!__any(sup)) {
                    if (lane == cnt) { kb0 = c4; kc0 = ccls; }
                    if (lane == cnt - 64) { kb1 = c4; kc1 = ccls; }
                    if (lane == 0) { kbox[cnt] = c4; selAnc[cnt] = a; }
                    cnt++;
                }
            }
            if (lane == 0) sv[5] = (unsigned)cnt;
        }
        __syncthreads();
        if (t == 0) sv[6] = (sv[5] < PROP && S < totalCand) ? 1u : 0u;
        __syncthreads();
        if (!sv[6]) break;
    }

    // outputs: out_logit [B][PROP][CC] then out_box [B][PROP][4]
    unsigned nk = sv[5];
    float* outL = out + (size_t)b * PROP * CC;
    const float* lgb = logits + (size_t)b * NC;
    const float* cb = cent + (size_t)b * NN;
    for (int s = t; s < PROP * CC; s += 256) {
        int p = s / CC;
        int c = s - p * CC;
        float v = 0.f;
        if ((unsigned)p < nk) {
            unsigned a = selAnc[p];
            v = sqrtf(lgb[(size_t)a * CC + c] * cb[a]);
        }
        outL[s] = v;
    }
    float* outB = out + (size_t)BB * PROP * CC + (size_t)b * PROP * 4;
    for (int s = t; s < PROP * 4; s += 256) {
        int p = s >> 2;
        float v = 0.f;
        if ((unsigned)p < nk) v = ((const float*)&kbox[p])[s & 3];
        outB[s] = v;
    }
}

extern "C" void kernel_launch(void* const* d_in, const int* in_sizes, int n_in,
                              void* d_out, int out_size, void* d_ws, size_t ws_size,
                              hipStream_t stream) {
    const float* logits  = (const float*)d_in[0];
    const float* regress = (const float*)d_in[1];
    const float* points  = (const float*)d_in[2];
    const float* cent    = (const float*)d_in[3];
    float* out = (float*)d_out;

    char* ws = (char*)d_ws;
    unsigned* hist = (unsigned*)ws;
    unsigned* ctrl = (unsigned*)(ws + CTRL_OFF);
    unsigned long long* candA = (unsigned long long*)(ws + CANDA_OFF);
    unsigned long long* candB = (unsigned long long*)(ws + CANDB_OFF);
    unsigned long long* spill = (unsigned long long*)(ws + SPILL_OFF);

    hipMemsetAsync(d_ws, 0, ZERO_BYTES, stream);
    if (ws_size >= WS_NEEDED) {
        k_pass1<<<dim3(512, BB), 256, 0, stream>>>(logits, cent, ctrl, spill);
        k_slowflag<<<1, 64, 0, stream>>>(ctrl);
        k_hist_spill<<<dim3(32, BB), 256, 0, stream>>>(ctrl, spill, hist);
        k_hist<<<dim3(256, BB), 256, 0, stream>>>(logits, cent, hist, ctrl);        // guarded slow path
        k_select<<<BB, 256, 0, stream>>>(hist, ctrl);                               // guarded slow path
        k_compact<<<dim3(256, BB), 256, 0, stream>>>(logits, cent, ctrl, candA, candB);  // guarded slow path
    } else {
        hipMemsetAsync(ws + CTRL_OFF + 28, 1, 1, stream);  // force validated full-scan path
        k_hist<<<dim3(256, BB), 256, 0, stream>>>(logits, cent, hist, ctrl);
        k_select<<<BB, 256, 0, stream>>>(hist, ctrl);
        k_compact<<<dim3(256, BB), 256, 0, stream>>>(logits, cent, ctrl, candA, candB);
    }
    k_mega<<<BB, 256, 0, stream>>>(logits, regress, points, cent, hist, ctrl, spill, candA, candB, out);
}